// Round 6
// baseline (823.770 us; speedup 1.0000x reference)
//
#include <hip/hip_runtime.h>
#include <hip/hip_bf16.h>
#include <math.h>

#define H     1024
#define FFN   4096
#define NE    8
#define TOK   2048
#define PAIRS (TOK*2)
#define BM    128
#define BK    32
#define ROWCAP (PAIRS + NE*BM)   /* 5120 worst-case padded rows */
#define MAXTILES (ROWCAP/BM)     /* 40 */
#define SPLITK 4

typedef unsigned short u16;
typedef __attribute__((ext_vector_type(8))) __bf16 bf16x8;
typedef __attribute__((ext_vector_type(4))) float  f32x4;

__device__ __forceinline__ unsigned cvt2(float a, float b) {
    __hip_bfloat162 h = __float22bfloat162_rn(float2{a, b});
    unsigned u;
    __builtin_memcpy(&u, &h, 4);
    return u;
}

#define GLD16(gp, lp) __builtin_amdgcn_global_load_lds( \
    (const __attribute__((address_space(1))) void*)(gp), \
    (__attribute__((address_space(3))) void*)(lp), 16, 0, 0)

// ---------------- kernel 0: convert weights fp32 -> bf16 (HBM-bound) ----------------
__global__ __launch_bounds__(256) void k_cvtw(const float4* __restrict__ w13,
                                              const float4* __restrict__ w2,
                                              uint4* __restrict__ o13,
                                              uint4* __restrict__ o2) {
    size_t i = (size_t)blockIdx.x * 256 + threadIdx.x;     // one per 8 floats
    const size_t N13 = (size_t)NE * 2 * FFN * H / 8;       // 8,388,608
    const float4* src; uint4* dst; size_t j;
    if (i < N13) { src = w13; dst = o13; j = i; }
    else         { src = w2;  dst = o2;  j = i - N13; }
    float4 a = src[2 * j], b = src[2 * j + 1];
    uint4 o = { cvt2(a.x, a.y), cvt2(a.z, a.w), cvt2(b.x, b.y), cvt2(b.z, b.w) };
    dst[j] = o;
}

// ---------------- kernel 1: init counts ----------------
__global__ void k_init(int* counts) {
    if (threadIdx.x < NE) counts[threadIdx.x] = 0;
}

// ---------------- kernel 2: router ----------------
__global__ void k_router(const float* __restrict__ x, const float* __restrict__ gw,
                         float* __restrict__ logits, int* counts,
                         int* __restrict__ sel, int* __restrict__ posn, float* __restrict__ wgt) {
    int lane = threadIdx.x & 63;
    int t = blockIdx.x * 4 + (threadIdx.x >> 6);
    float p[NE];
#pragma unroll
    for (int e = 0; e < NE; e++) p[e] = 0.f;
    for (int j = 0; j < H / 64; j++) {
        int h = lane + j * 64;
        float xv = x[(size_t)t * H + h];
#pragma unroll
        for (int e = 0; e < NE; e++) p[e] = fmaf(xv, gw[e * H + h], p[e]);
    }
#pragma unroll
    for (int off = 32; off; off >>= 1)
#pragma unroll
        for (int e = 0; e < NE; e++) p[e] += __shfl_xor(p[e], off, 64);
    if (lane == 0) {
        float mx = p[0];
#pragma unroll
        for (int e = 1; e < NE; e++) mx = fmaxf(mx, p[e]);
        float pe[NE];
#pragma unroll
        for (int e = 0; e < NE; e++) pe[e] = __expf(p[e] - mx);
        int i0 = 0;
#pragma unroll
        for (int e = 1; e < NE; e++) if (pe[e] > pe[i0]) i0 = e;
        int i1 = (i0 == 0) ? 1 : 0;
#pragma unroll
        for (int e = 0; e < NE; e++) if (e != i1 && e != i0 && pe[e] > pe[i1]) i1 = e;
        float w0 = pe[i0] / (pe[i0] + pe[i1]);
#pragma unroll
        for (int e = 0; e < NE; e++) logits[(size_t)t * NE + e] = p[e];
        int p0 = atomicAdd(&counts[i0], 1);
        int p1 = atomicAdd(&counts[i1], 1);
        sel[2 * t] = i0;  posn[2 * t] = p0;  wgt[2 * t] = w0;
        sel[2 * t + 1] = i1;  posn[2 * t + 1] = p1;  wgt[2 * t + 1] = 1.f - w0;
    }
}

// ---------------- kernel 3: prefix / tile map ----------------
__global__ void k_prefix(const int* __restrict__ counts, int* __restrict__ base,
                         int* __restrict__ tile_e) {
    if (threadIdx.x == 0) {
        int b = 0, tb = 0;
        for (int e = 0; e < NE; e++) {
            base[e] = b;
            int nt = (counts[e] + BM - 1) / BM;
            for (int i = 0; i < nt; i++) tile_e[tb++] = e;
            b += nt * BM;
        }
        base[NE] = b;
        while (tb < MAXTILES) tile_e[tb++] = -1;
    }
}

// ---------------- kernel 4: gather x -> bf16 compacted rows ----------------
// Pad rows of xg stay 0xAA-poisoned: bf16 0xAAAA = -1.2e-13 (finite); pad-row
// outputs are never read by k_combine, so no zeroing needed.
__global__ void k_gather(const float4* __restrict__ x4, const int* __restrict__ sel,
                         const int* __restrict__ posn, const int* __restrict__ base,
                         u16* __restrict__ xg) {
    int p = blockIdx.x;
    int lane = threadIdx.x;       // 64 threads
    int t = p >> 1;
    int row = base[sel[p]] + posn[p];
#pragma unroll
    for (int i = 0; i < 4; i++) {
        int idx = i * 64 + lane;  // float4 index within row (256 per row)
        float4 v = x4[(size_t)t * (H / 4) + idx];
        uint2 o = { cvt2(v.x, v.y), cvt2(v.z, v.w) };
        *(uint2*)&xg[(size_t)row * H + idx * 4] = o;
    }
}

// ---------------- kernel 5: GEMM1  act = silu(x w1^T) * (x w3^T) ----------------
// All tiles staged via global_load_lds x16B in MFMA-fragment order:
// fragment f (16B) lives at LDS offset f*16; ds_read_b128 is lane-contiguous
// -> zero bank conflicts. GLD16's global source address is free per-lane.
__global__ __launch_bounds__(256) void k_gemm1(const u16* __restrict__ xg,
                                               const u16* __restrict__ w13b,
                                               u16* __restrict__ act,
                                               const int* __restrict__ tile_e) {
    int e = tile_e[blockIdx.x];
    if (e < 0) return;
    __shared__ alignas(16) u16 As[4096];  // 512 frags: f = wm*256 + mi*64 + lane
    __shared__ alignas(16) u16 Bg[2048];  // 256 frags: f = wn*128 + ni*64 + lane
    __shared__ alignas(16) u16 Bu[2048];

    int tid = threadIdx.x;
    int lane = tid & 63, wave = tid >> 6;
    int quad = lane >> 4, m16 = lane & 15;
    int wm = wave >> 1, wn = wave & 1;
    int row0 = blockIdx.x * BM;
    int n0 = blockIdx.y * 64;
    const u16* xb  = xg + (size_t)row0 * H;
    const u16* wb1 = w13b + ((size_t)e * 2 * FFN + n0) * H;
    const u16* wb3 = w13b + ((size_t)e * 2 * FFN + FFN + n0) * H;

    f32x4 accg[4][2], accu[4][2];
#pragma unroll
    for (int mi = 0; mi < 4; mi++)
#pragma unroll
        for (int ni = 0; ni < 2; ni++) { accg[mi][ni] = {0.f,0.f,0.f,0.f}; accu[mi][ni] = {0.f,0.f,0.f,0.f}; }

    // fragment-order staging source indices (f = tid and f = tid + 256)
    int ar = ((tid >> 6) & 3) * 16 + (tid & 15);          // A row for f=tid (0..63)
    int ak = ((tid >> 4) & 3) * 8;                        // A k-offset
    int br = (tid >> 7) * 32 + ((tid >> 6) & 1) * 16 + (tid & 15);  // B row (0..63)

    for (int kk = 0; kk < H; kk += BK) {
        GLD16(xb + (size_t)ar * H + kk + ak, As + tid * 8);
        GLD16(xb + (size_t)(ar + 64) * H + kk + ak, As + 2048 + tid * 8);
        GLD16(wb1 + (size_t)br * H + kk + ak, Bg + tid * 8);
        GLD16(wb3 + (size_t)br * H + kk + ak, Bu + tid * 8);
        __syncthreads();
        bf16x8 a[4], bg[2], bu[2];
#pragma unroll
        for (int mi = 0; mi < 4; mi++)
            a[mi] = *(const bf16x8*)&As[(wm * 256 + mi * 64 + lane) * 8];
#pragma unroll
        for (int ni = 0; ni < 2; ni++) {
            bg[ni] = *(const bf16x8*)&Bg[(wn * 128 + ni * 64 + lane) * 8];
            bu[ni] = *(const bf16x8*)&Bu[(wn * 128 + ni * 64 + lane) * 8];
        }
#pragma unroll
        for (int mi = 0; mi < 4; mi++)
#pragma unroll
            for (int ni = 0; ni < 2; ni++) {
                accg[mi][ni] = __builtin_amdgcn_mfma_f32_16x16x32_bf16(a[mi], bg[ni], accg[mi][ni], 0, 0, 0);
                accu[mi][ni] = __builtin_amdgcn_mfma_f32_16x16x32_bf16(a[mi], bu[ni], accu[mi][ni], 0, 0, 0);
            }
        __syncthreads();
    }
    // epilogue: silu(g)*u -> bf16 act
#pragma unroll
    for (int mi = 0; mi < 4; mi++)
#pragma unroll
        for (int ni = 0; ni < 2; ni++) {
            int gcol = n0 + wn * 32 + ni * 16 + m16;
            int grow = row0 + wm * 64 + mi * 16 + quad * 4;
#pragma unroll
            for (int r = 0; r < 4; r++) {
                float g = accg[mi][ni][r], u = accu[mi][ni][r];
                float hv = g * (1.f / (1.f + __expf(-g))) * u;
                unsigned pk = cvt2(hv, hv);
                act[(size_t)(grow + r) * FFN + gcol] = (u16)(pk & 0xffff);
            }
        }
}

// ---------------- kernel 6: GEMM2  yc = act w2^T  (split-K = 4) ----------------
__global__ __launch_bounds__(256) void k_gemm2(const u16* __restrict__ act,
                                               const u16* __restrict__ w2b,
                                               float* __restrict__ yc,
                                               const int* __restrict__ tile_e) {
    int e = tile_e[blockIdx.x];
    if (e < 0) return;
    __shared__ alignas(16) u16 As[4096];  // frags f = wm*256 + mi*64 + lane
    __shared__ alignas(16) u16 Bs[4096];  // frags f = wn*256 + ni*64 + lane

    int tid = threadIdx.x;
    int lane = tid & 63, wave = tid >> 6;
    int quad = lane >> 4, m16 = lane & 15;
    int wm = wave >> 1, wn = wave & 1;
    int row0 = blockIdx.x * BM;
    int n0 = blockIdx.y * 128;
    int k0 = blockIdx.z * (FFN / SPLITK);
    const u16* ab = act + (size_t)row0 * FFN;
    const u16* wb = w2b + ((size_t)e * H + n0) * FFN;
    float* ycp = yc + (size_t)blockIdx.z * ROWCAP * H;

    f32x4 acc[4][4];
#pragma unroll
    for (int mi = 0; mi < 4; mi++)
#pragma unroll
        for (int ni = 0; ni < 4; ni++) acc[mi][ni] = {0.f,0.f,0.f,0.f};

    int ar = ((tid >> 6) & 3) * 16 + (tid & 15);   // rows 0..63 for f=tid
    int ak = ((tid >> 4) & 3) * 8;

    for (int kk = k0; kk < k0 + FFN / SPLITK; kk += BK) {
        GLD16(ab + (size_t)ar * FFN + kk + ak, As + tid * 8);
        GLD16(ab + (size_t)(ar + 64) * FFN + kk + ak, As + 2048 + tid * 8);
        GLD16(wb + (size_t)ar * FFN + kk + ak, Bs + tid * 8);
        GLD16(wb + (size_t)(ar + 64) * FFN + kk + ak, Bs + 2048 + tid * 8);
        __syncthreads();
        bf16x8 a[4], b[4];
#pragma unroll
        for (int mi = 0; mi < 4; mi++)
            a[mi] = *(const bf16x8*)&As[(wm * 256 + mi * 64 + lane) * 8];
#pragma unroll
        for (int ni = 0; ni < 4; ni++)
            b[ni] = *(const bf16x8*)&Bs[(wn * 256 + ni * 64 + lane) * 8];
#pragma unroll
        for (int mi = 0; mi < 4; mi++)
#pragma unroll
            for (int ni = 0; ni < 4; ni++)
                acc[mi][ni] = __builtin_amdgcn_mfma_f32_16x16x32_bf16(a[mi], b[ni], acc[mi][ni], 0, 0, 0);
        __syncthreads();
    }
#pragma unroll
    for (int mi = 0; mi < 4; mi++)
#pragma unroll
        for (int ni = 0; ni < 4; ni++)
#pragma unroll
            for (int r = 0; r < 4; r++) {
                int grow = row0 + wm * 64 + mi * 16 + quad * 4 + r;
                int gcol = n0 + wn * 64 + ni * 16 + m16;
                ycp[(size_t)grow * H + gcol] = acc[mi][ni][r];
            }
}

// ---------------- kernel 7: combine (sums split-K partials) ----------------
__global__ void k_combine(const float4* __restrict__ yc4, const int* __restrict__ sel,
                          const int* __restrict__ posn, const int* __restrict__ base,
                          const float* __restrict__ wgt, float4* __restrict__ out4) {
    int t = blockIdx.x;
    int j = threadIdx.x;  // 256, H/4
    int r0 = base[sel[2 * t]] + posn[2 * t];
    int r1 = base[sel[2 * t + 1]] + posn[2 * t + 1];
    float w0 = wgt[2 * t], w1 = wgt[2 * t + 1];
    const size_t P = (size_t)ROWCAP * (H / 4);
    float4 o = {0.f, 0.f, 0.f, 0.f};
#pragma unroll
    for (int z = 0; z < SPLITK; z++) {
        float4 a = yc4[(size_t)r0 * (H / 4) + j + z * P];
        float4 b = yc4[(size_t)r1 * (H / 4) + j + z * P];
        o.x += w0 * a.x + w1 * b.x;
        o.y += w0 * a.y + w1 * b.y;
        o.z += w0 * a.z + w1 * b.z;
        o.w += w0 * a.w + w1 * b.w;
    }
    out4[(size_t)t * (H / 4) + j] = o;
}

extern "C" void kernel_launch(void* const* d_in, const int* in_sizes, int n_in,
                              void* d_out, int out_size, void* d_ws, size_t ws_size,
                              hipStream_t stream) {
    const float* x   = (const float*)d_in[0];
    const float* gw  = (const float*)d_in[1];
    const float* w13 = (const float*)d_in[2];
    const float* w2  = (const float*)d_in[3];
    float* out    = (float*)d_out;
    float* logits = out + (size_t)TOK * H;

    char* ws = (char*)d_ws;
    int*   counts = (int*)ws;
    int*   base   = (int*)(ws + 256);
    int*   tile_e = (int*)(ws + 512);
    int*   sel    = (int*)(ws + 1024);
    int*   posn   = (int*)(ws + 1024 + 4 * PAIRS);
    float* wgt    = (float*)(ws + 1024 + 8 * PAIRS);
    u16*   xg     = (u16*)(ws + 131072);                      // 10.5 MB
    u16*   act    = xg + (size_t)ROWCAP * H;                  // 41.9 MB
    u16*   w13b   = act + (size_t)ROWCAP * FFN;               // 134.2 MB
    u16*   w2b    = w13b + (size_t)NE * 2 * FFN * H;          // 67.1 MB
    float* yc     = (float*)(w2b + (size_t)NE * H * FFN);     // 4 x 20.9 MB

    k_cvtw<<<49152, 256, 0, stream>>>((const float4*)w13, (const float4*)w2,
                                      (uint4*)w13b, (uint4*)w2b);
    k_init<<<1, 64, 0, stream>>>(counts);
    k_router<<<TOK / 4, 256, 0, stream>>>(x, gw, logits, counts, sel, posn, wgt);
    k_prefix<<<1, 64, 0, stream>>>(counts, base, tile_e);
    k_gather<<<PAIRS, 64, 0, stream>>>((const float4*)x, sel, posn, base, xg);
    dim3 g1(MAXTILES, FFN / 64);
    k_gemm1<<<g1, 256, 0, stream>>>(xg, w13b, act, tile_e);
    dim3 g2(MAXTILES, H / 128, SPLITK);
    k_gemm2<<<g2, 256, 0, stream>>>(act, w2b, yc, tile_e);
    k_combine<<<TOK, 256, 0, stream>>>((const float4*)yc, sel, posn, base, wgt, (float4*)out);
}